// Round 1
// baseline (595.076 us; speedup 1.0000x reference)
//
#include <hip/hip_runtime.h>
#include <math.h>

#define NN 2048
#define BB 8
#define HH 2
#define NEG 0.2f
#define EPSL 1e-5f

__device__ __forceinline__ float wave_reduce_sum(float v){
#pragma unroll
  for (int m = 32; m > 0; m >>= 1) v += __shfl_xor(v, m, 64);
  return v;
}

__global__ void k_zero_f(float* p, int n){ int i = blockIdx.x*256+threadIdx.x; if(i<n) p[i]=0.f; }
__global__ void k_zero_i(int* p, int n){ int i = blockIdx.x*256+threadIdx.x; if(i<n) p[i]=0; }

__global__ void k_count(const int* __restrict__ dst, int E, int* cnt){
  int i = blockIdx.x*256+threadIdx.x; if(i<E) atomicAdd(&cnt[dst[i]],1);
}

// single block, 256 threads: exclusive scan of 2048 counts
__global__ void k_scan(const int* __restrict__ cnt, int* row_start, int* cursor){
  __shared__ int part[256];
  int tid = threadIdx.x;
  int loc[8]; int s = 0;
#pragma unroll
  for(int j=0;j<8;j++){ loc[j]=s; s += cnt[tid*8+j]; }
  part[tid]=s; __syncthreads();
  for(int off=1; off<256; off<<=1){
    int v = (tid>=off)? part[tid-off] : 0;
    __syncthreads();
    part[tid] += v;
    __syncthreads();
  }
  int excl = (tid==0)? 0 : part[tid-1];
#pragma unroll
  for(int j=0;j<8;j++){ int v=excl+loc[j]; row_start[tid*8+j]=v; cursor[tid*8+j]=v; }
  if(tid==255) row_start[2048]=excl+s;
}

__global__ void k_fill(const int* __restrict__ dst, int E, int* cursor, int* csr){
  int i = blockIdx.x*256+threadIdx.x;
  if(i<E){ int p = atomicAdd(&cursor[dst[i]],1); csr[p]=i; }
}

// rows = (b*N+n)*TT+t over X[rows][64]; feat[rows][128] = X*W (opt. LN fused on load)
template<int TT, bool LN>
__global__ __launch_bounds__(256) void k_feat(
  const float* __restrict__ X, const float* __restrict__ W,
  const float* __restrict__ mu, const float* __restrict__ inv,
  const float* __restrict__ lnw, const float* __restrict__ lnb,
  float* __restrict__ feat)
{
  __shared__ float ws_[64*128];   // [k][d]
  __shared__ float xs[32][64];    // [row_local][k]
  int tid = threadIdx.x;
  int r0 = blockIdx.x*32;
  for(int i=tid;i<8192;i+=256) ws_[i] = W[i];
  for(int i=tid;i<2048;i+=256){
    int rl = i>>6, c = i&63; int row = r0+rl;
    float v = X[(size_t)row*64 + c];
    if constexpr (LN){
      int t = row % TT; int n_ = (row/TT) % NN; int b = row/(TT*NN);
      int g = b*TT + t;
      v = (v - mu[g])*inv[g]*lnw[n_*64+c] + lnb[n_*64+c];
    }
    xs[rl][c] = v;
  }
  __syncthreads();
  int d0  = (tid&31)*4;
  int rl0 = (tid>>5)*4;
  float acc[4][4];
#pragma unroll
  for(int i=0;i<4;i++){ acc[i][0]=0.f; acc[i][1]=0.f; acc[i][2]=0.f; acc[i][3]=0.f; }
#pragma unroll 4
  for(int k4=0;k4<16;k4++){
    float xvi[4][4];
#pragma unroll
    for(int i=0;i<4;i++){
      float4 t = *(const float4*)&xs[rl0+i][k4*4];
      xvi[i][0]=t.x; xvi[i][1]=t.y; xvi[i][2]=t.z; xvi[i][3]=t.w;
    }
#pragma unroll
    for(int kk=0;kk<4;kk++){
      float4 w4 = *(const float4*)&ws_[(k4*4+kk)*128 + d0];
#pragma unroll
      for(int i=0;i<4;i++){
        acc[i][0] += xvi[i][kk]*w4.x;
        acc[i][1] += xvi[i][kk]*w4.y;
        acc[i][2] += xvi[i][kk]*w4.z;
        acc[i][3] += xvi[i][kk]*w4.w;
      }
    }
  }
#pragma unroll
  for(int i=0;i<4;i++){
    float4 o; o.x=acc[i][0]; o.y=acc[i][1]; o.z=acc[i][2]; o.w=acc[i][3];
    *(float4*)&feat[((size_t)(r0+rl0+i))*128 + d0] = o;
  }
}

// el[row*2+h] = sum_c feat[row][h*64+c]*al[h*64+c]; er likewise. one wave per row.
__global__ __launch_bounds__(256) void k_elr(const float* __restrict__ feat,
  const float* __restrict__ al, const float* __restrict__ ar,
  float* __restrict__ el, float* __restrict__ er)
{
  int row = blockIdx.x*4 + (threadIdx.x>>6);
  int c = threadIdx.x & 63;
  float f0 = feat[(size_t)row*128 + c];
  float f1 = feat[(size_t)row*128 + 64 + c];
  float e0 = wave_reduce_sum(f0*al[c]);
  float r0 = wave_reduce_sum(f0*ar[c]);
  float e1 = wave_reduce_sum(f1*al[64+c]);
  float r1 = wave_reduce_sum(f1*ar[64+c]);
  if(c==0){ el[row*2]=e0; er[row*2]=r0; el[row*2+1]=e1; er[row*2+1]=r1; }
}

// one block per dst node: online softmax over in-edges + gather-aggregate + bias + relu
template<int TT>
__global__ __launch_bounds__(256) void k_gat_agg(
  const float* __restrict__ feat, const float* __restrict__ el, const float* __restrict__ er,
  const int* __restrict__ row_start, const int* __restrict__ csr, const int* __restrict__ srcA,
  const float* __restrict__ bias, float* __restrict__ out)
{
  constexpr int BTH = BB*TT*HH;       // 64 or 128
  constexpr int ACCN = BTH/4;         // BTH*64/256
  int n = blockIdx.x; int tid = threadIdx.x;
  int beg = row_start[n]; int deg = row_start[n+1]-beg;
  __shared__ float m_s[BTH], s_s[BTH], er_s[BTH];
  __shared__ int src_s[16];
  __shared__ float alpha_s[16][BTH];
  int ebase = 0;
  if(tid < BTH){
    int h = tid&1; int t = (tid>>1)%TT; int b = tid/(2*TT);
    ebase = ((b*NN)*TT + t)*2 + h;
    float ern = er[ebase + n*TT*2];
    float m = -3.0e38f, s = 0.f;
    for(int j=0;j<deg;j++){
      int eid = csr[beg+j]; int sn = srcA[eid];
      float e = el[ebase + sn*TT*2] + ern;
      e = e>0.f? e : NEG*e;
      float mn = fmaxf(m,e);
      s = s*__expf(m-mn) + __expf(e-mn);
      m = mn;
    }
    m_s[tid]=m; s_s[tid]=s; er_s[tid]=ern;
  }
  float acc[ACCN];
  int foff[ACCN];
  int c = tid&63; int rbase = tid>>6;
#pragma unroll
  for(int a=0;a<ACCN;a++){
    int rr = rbase + a*4;
    int h = rr&1; int t=(rr>>1)%TT; int b = rr/(2*TT);
    foff[a] = ((b*NN)*TT + t)*128 + h*64 + c;
    acc[a]=0.f;
  }
  __syncthreads();
  for(int c0=0;c0<deg;c0+=16){
    int cl = min(16, deg-c0);
    if(tid<cl) src_s[tid] = srcA[csr[beg+c0+tid]];
    __syncthreads();
    if(tid<BTH){
      float m = m_s[tid]; float sinv = 1.f/s_s[tid]; float ern = er_s[tid];
      for(int j=0;j<cl;j++){
        int sn = src_s[j];
        float e = el[ebase + sn*TT*2] + ern;
        e = e>0.f? e : NEG*e;
        alpha_s[j][tid] = __expf(e-m)*sinv;
      }
    }
    __syncthreads();
    for(int j=0;j<cl;j++){
      int sn = src_s[j];
      const float* fp = feat + (size_t)sn*(TT*128);
#pragma unroll
      for(int a=0;a<ACCN;a++){
        acc[a] += alpha_s[j][rbase + a*4] * fp[foff[a]];
      }
    }
    __syncthreads();
  }
#pragma unroll
  for(int a=0;a<ACCN;a++){
    int rr = rbase + a*4;
    int h = rr&1; int t=(rr>>1)%TT; int b = rr/(2*TT);
    float v = acc[a] + bias[h*64+c];
    v = fmaxf(v,0.f);
    out[(((size_t)b*NN + n)*(TT*2) + (t*2+h))*64 + c] = v;
  }
}

// partial sums for LN over (N,C) per group g=(b,tg). X layout [B,N,Tg,64]. 8 splits/group.
__global__ __launch_bounds__(256) void k_ln_part(const float* __restrict__ X, int Tg, float* __restrict__ sums)
{
  int g = blockIdx.x >> 3;
  int sp = blockIdx.x & 7;
  int b = g / Tg; int tg = g % Tg;
  size_t base = ((size_t)b*NN*Tg + tg)*64;
  int c = threadIdx.x & 63; int nsub = threadIdx.x>>6;
  float s=0.f, q=0.f;
  int n0 = sp*256;
  for(int k=0;k<64;k++){
    int n_ = n0 + nsub + k*4;
    float v = X[base + (size_t)n_*(Tg*64) + c];
    s += v; q += v*v;
  }
  s = wave_reduce_sum(s); q = wave_reduce_sum(q);
  __shared__ float red[8];
  int wid = threadIdx.x>>6; int lane = threadIdx.x&63;
  if(lane==0){ red[wid*2]=s; red[wid*2+1]=q; }
  __syncthreads();
  if(threadIdx.x==0){
    float S=0.f,Q=0.f;
    for(int w=0;w<4;w++){ S+=red[w*2]; Q+=red[w*2+1]; }
    atomicAdd(&sums[g*2], S); atomicAdd(&sums[g*2+1], Q);
  }
}

__global__ void k_ln_fin(const float* __restrict__ sums, float* __restrict__ mu, float* __restrict__ inv, int G){
  int g = threadIdx.x + blockIdx.x*256;
  if(g<G){
    float cnt = (float)(NN*64);
    float m = sums[g*2]/cnt;
    float v = sums[g*2+1]/cnt - m*m;
    mu[g]=m; inv[g]=rsqrtf(v+EPSL);
  }
}

// tc1: 5-tap conv over t (16->12), C->C, LN2 fused on x2 load. 4 (b,n) per block.
__global__ __launch_bounds__(256) void k_conv1(const float* __restrict__ x2,
  const float* __restrict__ mu, const float* __restrict__ inv,
  const float* __restrict__ lnw, const float* __restrict__ lnb,
  const float* __restrict__ w, const float* __restrict__ bias,
  float* __restrict__ y)
{
  __shared__ float xt[4][16][64];
  __shared__ float wk[64][64];   // [ci][co]
  int tid = threadIdx.x;
  int g0 = blockIdx.x*4;
  for(int i=tid;i<4096;i+=256){
    int nd = i>>10; int rem = i&1023; int t = rem>>6; int cc_ = rem&63;
    int bn = g0+nd; int b = bn>>11; int n_ = bn&2047;
    float v = x2[((size_t)bn*16 + t)*64 + cc_];
    int g = b*16+t;
    v = (v-mu[g])*inv[g]*lnw[n_*64+cc_] + lnb[n_*64+cc_];
    xt[nd][t][cc_] = v;
  }
  int nd = tid>>6; int co4 = (tid&15)*4; int tq = (tid>>4)&3;
  float acc[3][4];
#pragma unroll
  for(int q=0;q<3;q++){ acc[q][0]=0.f; acc[q][1]=0.f; acc[q][2]=0.f; acc[q][3]=0.f; }
  for(int k=0;k<5;k++){
    __syncthreads();
    for(int i=tid;i<4096;i+=256){
      int ci = i>>6; int co = i&63;
      wk[ci][co] = w[(co*64+ci)*5 + k];
    }
    __syncthreads();
#pragma unroll 4
    for(int ci4=0;ci4<16;ci4++){
      float xv[3][4];
#pragma unroll
      for(int q=0;q<3;q++){
        float4 xq = *(const float4*)&xt[nd][tq*3+q+k][ci4*4];
        xv[q][0]=xq.x; xv[q][1]=xq.y; xv[q][2]=xq.z; xv[q][3]=xq.w;
      }
#pragma unroll
      for(int ii=0;ii<4;ii++){
        float4 wv = *(const float4*)&wk[ci4*4+ii][co4];
#pragma unroll
        for(int q=0;q<3;q++){
          acc[q][0] += xv[q][ii]*wv.x;
          acc[q][1] += xv[q][ii]*wv.y;
          acc[q][2] += xv[q][ii]*wv.z;
          acc[q][3] += xv[q][ii]*wv.w;
        }
      }
    }
  }
  int bn = g0+nd;
#pragma unroll
  for(int q=0;q<3;q++){
    int t = tq*3+q;
    float4 o;
    o.x=acc[q][0]+bias[co4];   o.y=acc[q][1]+bias[co4+1];
    o.z=acc[q][2]+bias[co4+2]; o.w=acc[q][3]+bias[co4+3];
    *(float4*)&y[((size_t)bn*12 + t)*64 + co4] = o;
  }
}

// tc2: 1x1 conv C->C with LN3 fused on x_t1 load. 4 (b,n) per block.
__global__ __launch_bounds__(256) void k_tc2(const float* __restrict__ x1t,
  const float* __restrict__ mu, const float* __restrict__ inv,
  const float* __restrict__ lnw, const float* __restrict__ lnb,
  const float* __restrict__ w, const float* __restrict__ bias,
  float* __restrict__ y)
{
  __shared__ float xt[4][12][64];
  __shared__ float wk[64][64];  // [ci][co]
  int tid = threadIdx.x;
  int g0 = blockIdx.x*4;
  for(int i=tid;i<3072;i+=256){
    int nd = i/768; int rem = i%768; int t = rem>>6; int cc_ = rem&63;
    int bn = g0+nd; int b = bn>>11; int n_ = bn&2047;
    float v = x1t[((size_t)bn*12 + t)*64 + cc_];
    int g = b*12+t;
    v = (v-mu[g])*inv[g]*lnw[n_*64+cc_] + lnb[n_*64+cc_];
    xt[nd][t][cc_] = v;
  }
  for(int i=tid;i<4096;i+=256){ int ci=i>>6; int co=i&63; wk[ci][co]=w[co*64+ci]; }
  __syncthreads();
  int nd = tid>>6; int co4 = (tid&15)*4; int tq = (tid>>4)&3;
  float acc[3][4];
#pragma unroll
  for(int q=0;q<3;q++){ acc[q][0]=0.f; acc[q][1]=0.f; acc[q][2]=0.f; acc[q][3]=0.f; }
#pragma unroll 4
  for(int ci4=0;ci4<16;ci4++){
    float xv[3][4];
#pragma unroll
    for(int q=0;q<3;q++){
      float4 xq = *(const float4*)&xt[nd][tq*3+q][ci4*4];
      xv[q][0]=xq.x; xv[q][1]=xq.y; xv[q][2]=xq.z; xv[q][3]=xq.w;
    }
#pragma unroll
    for(int ii=0;ii<4;ii++){
      float4 wv = *(const float4*)&wk[ci4*4+ii][co4];
#pragma unroll
      for(int q=0;q<3;q++){
        acc[q][0] += xv[q][ii]*wv.x;
        acc[q][1] += xv[q][ii]*wv.y;
        acc[q][2] += xv[q][ii]*wv.z;
        acc[q][3] += xv[q][ii]*wv.w;
      }
    }
  }
  int bn = g0+nd;
#pragma unroll
  for(int q=0;q<3;q++){
    int t = tq*3+q;
    float4 o;
    o.x=acc[q][0]+bias[co4];   o.y=acc[q][1]+bias[co4+1];
    o.z=acc[q][2]+bias[co4+2]; o.w=acc[q][3]+bias[co4+3];
    *(float4*)&y[((size_t)bn*12 + t)*64 + co4] = o;
  }
}

// final fc; exploits that the torch reshape is a linear view of [B,C,N,12].
// block = (b, nh); out[b, c*32+nh, o] = sum_{nl,t} xt2[b, nh*64+nl, t, c]*fw[o, nl*12+t] + fb[o]
__global__ __launch_bounds__(256) void k_fc(const float* __restrict__ xt2,
  const float* __restrict__ fw, const float* __restrict__ fb, float* __restrict__ out)
{
  __shared__ float fws[12][772];
  __shared__ float ch[8][768];
  int tid = threadIdx.x;
  int b = blockIdx.x>>5; int nh = blockIdx.x&31;
  for(int i=tid;i<9216;i+=256){ fws[i/768][i%768] = fw[i]; }
  float acc[3]; int cidx[3], oidx[3];
#pragma unroll
  for(int k=0;k<3;k++){ int oi = tid + k*256; cidx[k]=oi/12; oidx[k]=oi%12; acc[k]=0.f; }
  for(int c0=0;c0<64;c0+=8){
    __syncthreads();
    for(int i=tid;i<6144;i+=256){
      int nl = i/768; int r = i%768;
      ch[nl][r] = xt2[((size_t)(b*2048 + nh*64 + c0+nl))*768 + r];
    }
    __syncthreads();
    for(int nl=0;nl<8;nl++){
#pragma unroll
      for(int t=0;t<12;t++){
#pragma unroll
        for(int k=0;k<3;k++){
          acc[k] += ch[nl][t*64 + cidx[k]] * fws[oidx[k]][(c0+nl)*12 + t];
        }
      }
    }
  }
#pragma unroll
  for(int k=0;k<3;k++){
    int nprime = cidx[k]*32 + nh;
    out[((size_t)b*2048 + nprime)*12 + oidx[k]] = acc[k] + fb[oidx[k]];
  }
}

extern "C" void kernel_launch(void* const* d_in, const int* in_sizes, int n_in,
                              void* d_out, int out_size, void* d_ws, size_t ws_size,
                              hipStream_t stream) {
  (void)n_in; (void)out_size; (void)ws_size;
  const float* x    = (const float*)d_in[0];
  const int*   src  = (const int*)d_in[1];
  const int*   dst  = (const int*)d_in[2];
  const float* W1   = (const float*)d_in[3];
  const float* al1  = (const float*)d_in[4];
  const float* ar1  = (const float*)d_in[5];
  const float* b1   = (const float*)d_in[6];
  const float* W2   = (const float*)d_in[7];
  const float* al2  = (const float*)d_in[8];
  const float* ar2  = (const float*)d_in[9];
  const float* b2   = (const float*)d_in[10];
  const float* ln1w = (const float*)d_in[11];
  const float* ln1b = (const float*)d_in[12];
  const float* ln2w = (const float*)d_in[13];
  const float* ln2b = (const float*)d_in[14];
  const float* tc1w = (const float*)d_in[15];
  const float* tc1b = (const float*)d_in[16];
  const float* ln3w = (const float*)d_in[17];
  const float* ln3b = (const float*)d_in[18];
  const float* tc2w = (const float*)d_in[19];
  const float* tc2b = (const float*)d_in[20];
  const float* fcw  = (const float*)d_in[21];
  const float* fcb  = (const float*)d_in[22];
  int E = in_sizes[1];

  float* W = (float*)d_ws;
  // layout (floats):
  // [0 .. 16.78M)      feat (feat1 uses 8.39M; feat2 full). later: x_t1 at 0, x_t2 at 12.58M
  // [16.78M .. 25.17M) x1
  // [25.17M .. 41.94M) x2
  // then el/er, stats, int scratch
  float* feat = W + 0;
  float* x1   = W + 16777216;
  float* x2   = W + 25165824;
  float* xt1  = W + 0;          // reuses feat region after GAT2
  float* xt2  = W + 12582912;   // reuses feat tail + x1 region
  float* el1  = W + 41943040;
  float* er1  = el1 + 131072;
  float* el2  = er1 + 131072;
  float* er2  = el2 + 262144;
  float* stats = er2 + 262144;       // 1152 floats total
  float* sums1 = stats;              // 128
  float* mu1   = sums1 + 128;        // 64
  float* inv1  = mu1 + 64;           // 64
  float* sums2 = inv1 + 64;          // 256
  float* mu2   = sums2 + 256;        // 128
  float* inv2  = mu2 + 128;          // 128
  float* sums3 = inv2 + 128;         // 192
  float* mu3   = sums3 + 192;        // 96
  float* inv3  = mu3 + 96;           // 96
  int* counts  = (int*)(stats + 1152);
  int* cursor  = counts + 2048;
  int* rs      = cursor + 2048;      // 2049
  int* csr     = rs + 2049;          // E

  int eb = (E+255)/256;

  // CSR build (keyed by dst)
  k_zero_i<<<8,256,0,stream>>>(counts, 2048);
  k_zero_f<<<5,256,0,stream>>>(stats, 1152);
  k_count<<<eb,256,0,stream>>>(dst, E, counts);
  k_scan<<<1,256,0,stream>>>(counts, rs, cursor);
  k_fill<<<eb,256,0,stream>>>(dst, E, cursor, csr);

  // GAT layer 1
  k_feat<4,false><<<2048,256,0,stream>>>(x, W1, nullptr,nullptr,nullptr,nullptr, feat);
  k_elr<<<16384,256,0,stream>>>(feat, al1, ar1, el1, er1);
  k_gat_agg<4><<<2048,256,0,stream>>>(feat, el1, er1, rs, csr, src, b1, x1);

  // LN1 stats (apply fused into k_feat<8,true>)
  k_ln_part<<<512,256,0,stream>>>(x1, 8, sums1);
  k_ln_fin<<<1,256,0,stream>>>(sums1, mu1, inv1, 64);

  // GAT layer 2
  k_feat<8,true><<<4096,256,0,stream>>>(x1, W2, mu1, inv1, ln1w, ln1b, feat);
  k_elr<<<32768,256,0,stream>>>(feat, al2, ar2, el2, er2);
  k_gat_agg<8><<<2048,256,0,stream>>>(feat, el2, er2, rs, csr, src, b2, x2);

  // LN2 stats (apply fused into conv1)
  k_ln_part<<<1024,256,0,stream>>>(x2, 16, sums2);
  k_ln_fin<<<1,256,0,stream>>>(sums2, mu2, inv2, 128);

  // tc1 (16 -> 12 taps)
  k_conv1<<<4096,256,0,stream>>>(x2, mu2, inv2, ln2w, ln2b, tc1w, tc1b, xt1);

  // LN3 stats (apply fused into tc2)
  k_ln_part<<<768,256,0,stream>>>(xt1, 12, sums3);
  k_ln_fin<<<1,256,0,stream>>>(sums3, mu3, inv3, 96);

  // tc2 (1x1)
  k_tc2<<<4096,256,0,stream>>>(xt1, mu3, inv3, ln3w, ln3b, tc2w, tc2b, xt2);

  // final fc
  k_fc<<<256,256,0,stream>>>(xt2, fcw, fcb, (float*)d_out);
}

// Round 2
// 381.892 us; speedup vs baseline: 1.5582x; 1.5582x over previous
//
#include <hip/hip_runtime.h>
#include <math.h>

#define NN 2048
#define BB 8
#define HH 2
#define NEG 0.2f
#define EPSL 1e-5f

typedef short bf16x8 __attribute__((ext_vector_type(8)));
typedef float f32x4 __attribute__((ext_vector_type(4)));

__device__ __forceinline__ float wave_reduce_sum(float v){
#pragma unroll
  for (int m = 32; m > 0; m >>= 1) v += __shfl_xor(v, m, 64);
  return v;
}

__device__ __forceinline__ unsigned short f2b(float f){
  union { float f; unsigned u; } v; v.f = f;
  unsigned r = v.u + 0x7FFFu + ((v.u >> 16) & 1u);
  return (unsigned short)(r >> 16);
}

__global__ void k_zero_f(float* p, int n){ int i = blockIdx.x*256+threadIdx.x; if(i<n) p[i]=0.f; }
__global__ void k_zero_i(int* p, int n){ int i = blockIdx.x*256+threadIdx.x; if(i<n) p[i]=0; }

__global__ void k_count(const int* __restrict__ dst, int E, int* cnt){
  int i = blockIdx.x*256+threadIdx.x; if(i<E) atomicAdd(&cnt[dst[i]],1);
}

// single block, 256 threads: exclusive scan of 2048 counts
__global__ void k_scan(const int* __restrict__ cnt, int* row_start, int* cursor){
  __shared__ int part[256];
  int tid = threadIdx.x;
  int loc[8]; int s = 0;
#pragma unroll
  for(int j=0;j<8;j++){ loc[j]=s; s += cnt[tid*8+j]; }
  part[tid]=s; __syncthreads();
  for(int off=1; off<256; off<<=1){
    int v = (tid>=off)? part[tid-off] : 0;
    __syncthreads();
    part[tid] += v;
    __syncthreads();
  }
  int excl = (tid==0)? 0 : part[tid-1];
#pragma unroll
  for(int j=0;j<8;j++){ int v=excl+loc[j]; row_start[tid*8+j]=v; cursor[tid*8+j]=v; }
  if(tid==255) row_start[2048]=excl+s;
}

__global__ void k_fill(const int* __restrict__ dst, int E, int* cursor, int* csr){
  int i = blockIdx.x*256+threadIdx.x;
  if(i<E){ int p = atomicAdd(&cursor[dst[i]],1); csr[p]=i; }
}

// rows = (b*N+n)*TT+t over X[rows][64]; feat[rows][128] = X*W (opt. LN fused on load)
template<int TT, bool LN>
__global__ __launch_bounds__(256) void k_feat(
  const float* __restrict__ X, const float* __restrict__ W,
  const float* __restrict__ mu, const float* __restrict__ inv,
  const float* __restrict__ lnw, const float* __restrict__ lnb,
  float* __restrict__ feat)
{
  __shared__ float ws_[64*128];   // [k][d]
  __shared__ float xs[32][64];    // [row_local][k]
  int tid = threadIdx.x;
  int r0 = blockIdx.x*32;
  for(int i=tid;i<8192;i+=256) ws_[i] = W[i];
  for(int i=tid;i<2048;i+=256){
    int rl = i>>6, c = i&63; int row = r0+rl;
    float v = X[(size_t)row*64 + c];
    if constexpr (LN){
      int t = row % TT; int n_ = (row/TT) % NN; int b = row/(TT*NN);
      int g = b*TT + t;
      v = (v - mu[g])*inv[g]*lnw[n_*64+c] + lnb[n_*64+c];
    }
    xs[rl][c] = v;
  }
  __syncthreads();
  int d0  = (tid&31)*4;
  int rl0 = (tid>>5)*4;
  float acc[4][4];
#pragma unroll
  for(int i=0;i<4;i++){ acc[i][0]=0.f; acc[i][1]=0.f; acc[i][2]=0.f; acc[i][3]=0.f; }
#pragma unroll 4
  for(int k4=0;k4<16;k4++){
    float xvi[4][4];
#pragma unroll
    for(int i=0;i<4;i++){
      float4 t = *(const float4*)&xs[rl0+i][k4*4];
      xvi[i][0]=t.x; xvi[i][1]=t.y; xvi[i][2]=t.z; xvi[i][3]=t.w;
    }
#pragma unroll
    for(int kk=0;kk<4;kk++){
      float4 w4 = *(const float4*)&ws_[(k4*4+kk)*128 + d0];
#pragma unroll
      for(int i=0;i<4;i++){
        acc[i][0] += xvi[i][kk]*w4.x;
        acc[i][1] += xvi[i][kk]*w4.y;
        acc[i][2] += xvi[i][kk]*w4.z;
        acc[i][3] += xvi[i][kk]*w4.w;
      }
    }
  }
#pragma unroll
  for(int i=0;i<4;i++){
    float4 o; o.x=acc[i][0]; o.y=acc[i][1]; o.z=acc[i][2]; o.w=acc[i][3];
    *(float4*)&feat[((size_t)(r0+rl0+i))*128 + d0] = o;
  }
}

// el[row*2+h] = sum_c feat[row][h*64+c]*al[h*64+c]; er likewise. one wave per row.
__global__ __launch_bounds__(256) void k_elr(const float* __restrict__ feat,
  const float* __restrict__ al, const float* __restrict__ ar,
  float* __restrict__ el, float* __restrict__ er)
{
  int row = blockIdx.x*4 + (threadIdx.x>>6);
  int c = threadIdx.x & 63;
  float f0 = feat[(size_t)row*128 + c];
  float f1 = feat[(size_t)row*128 + 64 + c];
  float e0 = wave_reduce_sum(f0*al[c]);
  float r0 = wave_reduce_sum(f0*ar[c]);
  float e1 = wave_reduce_sum(f1*al[64+c]);
  float r1 = wave_reduce_sum(f1*ar[64+c]);
  if(c==0){ el[row*2]=e0; er[row*2]=r0; el[row*2+1]=e1; er[row*2+1]=r1; }
}

// one block per dst node: online softmax over in-edges + gather-aggregate + bias + relu
template<int TT>
__global__ __launch_bounds__(256) void k_gat_agg(
  const float* __restrict__ feat, const float* __restrict__ el, const float* __restrict__ er,
  const int* __restrict__ row_start, const int* __restrict__ csr, const int* __restrict__ srcA,
  const float* __restrict__ bias, float* __restrict__ out)
{
  constexpr int BTH = BB*TT*HH;       // 64 or 128
  constexpr int ACCN = BTH/4;         // BTH*64/256
  int n = blockIdx.x; int tid = threadIdx.x;
  int beg = row_start[n]; int deg = row_start[n+1]-beg;
  __shared__ float m_s[BTH], s_s[BTH], er_s[BTH];
  __shared__ int src_s[16];
  __shared__ float alpha_s[16][BTH];
  int ebase = 0;
  if(tid < BTH){
    int h = tid&1; int t = (tid>>1)%TT; int b = tid/(2*TT);
    ebase = ((b*NN)*TT + t)*2 + h;
    float ern = er[ebase + n*TT*2];
    float m = -3.0e38f, s = 0.f;
    for(int j=0;j<deg;j++){
      int eid = csr[beg+j]; int sn = srcA[eid];
      float e = el[ebase + sn*TT*2] + ern;
      e = e>0.f? e : NEG*e;
      float mn = fmaxf(m,e);
      s = s*__expf(m-mn) + __expf(e-mn);
      m = mn;
    }
    m_s[tid]=m; s_s[tid]=s; er_s[tid]=ern;
  }
  float acc[ACCN];
  int foff[ACCN];
  int c = tid&63; int rbase = tid>>6;
#pragma unroll
  for(int a=0;a<ACCN;a++){
    int rr = rbase + a*4;
    int h = rr&1; int t=(rr>>1)%TT; int b = rr/(2*TT);
    foff[a] = ((b*NN)*TT + t)*128 + h*64 + c;
    acc[a]=0.f;
  }
  __syncthreads();
  for(int c0=0;c0<deg;c0+=16){
    int cl = min(16, deg-c0);
    if(tid<cl) src_s[tid] = srcA[csr[beg+c0+tid]];
    __syncthreads();
    if(tid<BTH){
      float m = m_s[tid]; float sinv = 1.f/s_s[tid]; float ern = er_s[tid];
      for(int j=0;j<cl;j++){
        int sn = src_s[j];
        float e = el[ebase + sn*TT*2] + ern;
        e = e>0.f? e : NEG*e;
        alpha_s[j][tid] = __expf(e-m)*sinv;
      }
    }
    __syncthreads();
    for(int j=0;j<cl;j++){
      int sn = src_s[j];
      const float* fp = feat + (size_t)sn*(TT*128);
#pragma unroll
      for(int a=0;a<ACCN;a++){
        acc[a] += alpha_s[j][rbase + a*4] * fp[foff[a]];
      }
    }
    __syncthreads();
  }
#pragma unroll
  for(int a=0;a<ACCN;a++){
    int rr = rbase + a*4;
    int h = rr&1; int t=(rr>>1)%TT; int b = rr/(2*TT);
    float v = acc[a] + bias[h*64+c];
    v = fmaxf(v,0.f);
    out[(((size_t)b*NN + n)*(TT*2) + (t*2+h))*64 + c] = v;
  }
}

// partial sums for LN over (N,C) per group g=(b,tg). X layout [B,N,Tg,64]. 8 splits/group.
__global__ __launch_bounds__(256) void k_ln_part(const float* __restrict__ X, int Tg, float* __restrict__ sums)
{
  int g = blockIdx.x >> 3;
  int sp = blockIdx.x & 7;
  int b = g / Tg; int tg = g % Tg;
  size_t base = ((size_t)b*NN*Tg + tg)*64;
  int c = threadIdx.x & 63; int nsub = threadIdx.x>>6;
  float s=0.f, q=0.f;
  int n0 = sp*256;
  for(int k=0;k<64;k++){
    int n_ = n0 + nsub + k*4;
    float v = X[base + (size_t)n_*(Tg*64) + c];
    s += v; q += v*v;
  }
  s = wave_reduce_sum(s); q = wave_reduce_sum(q);
  __shared__ float red[8];
  int wid = threadIdx.x>>6; int lane = threadIdx.x&63;
  if(lane==0){ red[wid*2]=s; red[wid*2+1]=q; }
  __syncthreads();
  if(threadIdx.x==0){
    float S=0.f,Q=0.f;
    for(int w=0;w<4;w++){ S+=red[w*2]; Q+=red[w*2+1]; }
    atomicAdd(&sums[g*2], S); atomicAdd(&sums[g*2+1], Q);
  }
}

__global__ void k_ln_fin(const float* __restrict__ sums, float* __restrict__ mu, float* __restrict__ inv, int G){
  int g = threadIdx.x + blockIdx.x*256;
  if(g<G){
    float cnt = (float)(NN*64);
    float m = sums[g*2]/cnt;
    float v = sums[g*2+1]/cnt - m*m;
    mu[g]=m; inv[g]=rsqrtf(v+EPSL);
  }
}

// Temporal conv as MFMA GEMM, LN fused on input load.
// y[m=(bn,t_out)][co] = sum_{kap=(ktap,ci)} LN(x)[bn][t_out+ktap][ci] * w[co][ci][ktap]
// M = 16384*TOUT rows, N = 64, K = KT*64. 128 rows/block, 4 waves x (32 rows x 64 co).
template<int TIN, int TOUT, int KT>
__global__ __launch_bounds__(256) void k_convT(
  const float* __restrict__ xin,   // [BN][TIN][64]
  const float* __restrict__ mu, const float* __restrict__ inv,
  const float* __restrict__ lnw, const float* __restrict__ lnb,
  const float* __restrict__ w,     // [co][ci][1][KT]
  const float* __restrict__ bias,
  float* __restrict__ y)           // [BN][TOUT][64]
{
  constexpr int K = KT*64;
  constexpr int KSTEPS = K/32;
  constexpr int KPAD = K + 24;        // stride ≡ 12 banks (mod 32): 2-way max
  constexpr int XPAD = 88;            // 64+24, same property
  constexpr int XN = TIN*XPAD + 8;
  constexpr int NODES = 12;
  __shared__ __align__(16) unsigned short xs[NODES*XN];
  __shared__ __align__(16) unsigned short wt[64*KPAD];
  int tid = threadIdx.x;
  int r0 = blockIdx.x*128;
  int bn0 = r0/TOUT;

  // stage weights: wt[co][ktap*64+ci]
  for(int idx = tid; idx < 64*K; idx += 256){
    int co = idx/K; int kap = idx - co*K;
    int ktap = kap >> 6; int ci = kap & 63;
    wt[co*KPAD + kap] = f2b(w[(co*64+ci)*KT + ktap]);
  }
  // stage X with LN (float4 per thread-item)
  for(int idx = tid; idx < NODES*TIN*16; idx += 256){
    int nd = idx/(TIN*16); int rem = idx - nd*(TIN*16);
    int t = rem>>4; int c4 = (rem&15)*4;
    int bn = bn0+nd;
    if(bn < 16384){
      int b = bn>>11; int n_ = bn&2047; int g = b*TIN+t;
      float4 v = *(const float4*)&xin[((size_t)bn*TIN+t)*64 + c4];
      float4 wv = *(const float4*)&lnw[n_*64+c4];
      float4 bv = *(const float4*)&lnb[n_*64+c4];
      float m_ = mu[g], iv = inv[g];
      unsigned short* p = &xs[nd*XN + t*XPAD + c4];
      p[0]=f2b((v.x-m_)*iv*wv.x+bv.x);
      p[1]=f2b((v.y-m_)*iv*wv.y+bv.y);
      p[2]=f2b((v.z-m_)*iv*wv.z+bv.z);
      p[3]=f2b((v.w-m_)*iv*wv.w+bv.w);
    }
  }
  __syncthreads();

  int wv_ = tid>>6; int lane = tid&63;
  int lhi = lane>>4; int llo = lane&15;
  int nodeA[2], tA[2];
#pragma unroll
  for(int rt=0; rt<2; rt++){
    int r = r0 + wv_*32 + rt*16 + llo;
    int nd = r/TOUT;
    nodeA[rt] = nd - bn0; tA[rt] = r - nd*TOUT;
  }
  f32x4 acc[2][4];
#pragma unroll
  for(int i=0;i<2;i++)
#pragma unroll
    for(int j=0;j<4;j++) acc[i][j] = (f32x4){0.f,0.f,0.f,0.f};

#pragma unroll
  for(int s=0; s<KSTEPS; s++){
    int ktap = s>>1; int cib = ((s&1)<<5) + lhi*8;
    bf16x8 a0 = *(const bf16x8*)&xs[nodeA[0]*XN + (tA[0]+ktap)*XPAD + cib];
    bf16x8 a1 = *(const bf16x8*)&xs[nodeA[1]*XN + (tA[1]+ktap)*XPAD + cib];
    int kb = s*32 + lhi*8;
#pragma unroll
    for(int ct=0; ct<4; ct++){
      bf16x8 bfr = *(const bf16x8*)&wt[(ct*16+llo)*KPAD + kb];
      acc[0][ct] = __builtin_amdgcn_mfma_f32_16x16x32_bf16(a0, bfr, acc[0][ct], 0,0,0);
      acc[1][ct] = __builtin_amdgcn_mfma_f32_16x16x32_bf16(a1, bfr, acc[1][ct], 0,0,0);
    }
  }
#pragma unroll
  for(int rt=0; rt<2; rt++){
    int rbase = r0 + wv_*32 + rt*16 + lhi*4;
#pragma unroll
    for(int ct=0; ct<4; ct++){
      int co = ct*16 + llo;
      float bb = bias[co];
#pragma unroll
      for(int i=0;i<4;i++){
        y[(size_t)(rbase+i)*64 + co] = acc[rt][ct][i] + bb;
      }
    }
  }
}

// final fc; exploits that the torch reshape is a linear view of [B,C,N,12].
// block = (b, nh); out[b, c*32+nh, o] = sum_{nl,t} xt2[b, nh*64+nl, t, c]*fw[o, nl*12+t] + fb[o]
__global__ __launch_bounds__(256) void k_fc(const float* __restrict__ xt2,
  const float* __restrict__ fw, const float* __restrict__ fb, float* __restrict__ out)
{
  __shared__ float fws[12][772];
  __shared__ float ch[8][768];
  int tid = threadIdx.x;
  int b = blockIdx.x>>5; int nh = blockIdx.x&31;
  for(int i=tid;i<9216;i+=256){ fws[i/768][i%768] = fw[i]; }
  float acc[3]; int cidx[3], oidx[3];
#pragma unroll
  for(int k=0;k<3;k++){ int oi = tid + k*256; cidx[k]=oi/12; oidx[k]=oi%12; acc[k]=0.f; }
  for(int c0=0;c0<64;c0+=8){
    __syncthreads();
    for(int i=tid;i<6144;i+=256){
      int nl = i/768; int r = i%768;
      ch[nl][r] = xt2[((size_t)(b*2048 + nh*64 + c0+nl))*768 + r];
    }
    __syncthreads();
    for(int nl=0;nl<8;nl++){
#pragma unroll
      for(int t=0;t<12;t++){
#pragma unroll
        for(int k=0;k<3;k++){
          acc[k] += ch[nl][t*64 + cidx[k]] * fws[oidx[k]][(c0+nl)*12 + t];
        }
      }
    }
  }
#pragma unroll
  for(int k=0;k<3;k++){
    int nprime = cidx[k]*32 + nh;
    out[((size_t)b*2048 + nprime)*12 + oidx[k]] = acc[k] + fb[oidx[k]];
  }
}

extern "C" void kernel_launch(void* const* d_in, const int* in_sizes, int n_in,
                              void* d_out, int out_size, void* d_ws, size_t ws_size,
                              hipStream_t stream) {
  (void)n_in; (void)out_size; (void)ws_size;
  const float* x    = (const float*)d_in[0];
  const int*   src  = (const int*)d_in[1];
  const int*   dst  = (const int*)d_in[2];
  const float* W1   = (const float*)d_in[3];
  const float* al1  = (const float*)d_in[4];
  const float* ar1  = (const float*)d_in[5];
  const float* b1   = (const float*)d_in[6];
  const float* W2   = (const float*)d_in[7];
  const float* al2  = (const float*)d_in[8];
  const float* ar2  = (const float*)d_in[9];
  const float* b2   = (const float*)d_in[10];
  const float* ln1w = (const float*)d_in[11];
  const float* ln1b = (const float*)d_in[12];
  const float* ln2w = (const float*)d_in[13];
  const float* ln2b = (const float*)d_in[14];
  const float* tc1w = (const float*)d_in[15];
  const float* tc1b = (const float*)d_in[16];
  const float* ln3w = (const float*)d_in[17];
  const float* ln3b = (const float*)d_in[18];
  const float* tc2w = (const float*)d_in[19];
  const float* tc2b = (const float*)d_in[20];
  const float* fcw  = (const float*)d_in[21];
  const float* fcb  = (const float*)d_in[22];
  int E = in_sizes[1];

  float* W = (float*)d_ws;
  float* feat = W + 0;
  float* x1   = W + 16777216;
  float* x2   = W + 25165824;
  float* xt1  = W + 0;          // reuses feat region after GAT2
  float* xt2  = W + 12582912;   // reuses feat tail + x1 region
  float* el1  = W + 41943040;
  float* er1  = el1 + 131072;
  float* el2  = er1 + 131072;
  float* er2  = el2 + 262144;
  float* stats = er2 + 262144;
  float* sums1 = stats;              // 128
  float* mu1   = sums1 + 128;        // 64
  float* inv1  = mu1 + 64;           // 64
  float* sums2 = inv1 + 64;          // 256
  float* mu2   = sums2 + 256;        // 128
  float* inv2  = mu2 + 128;          // 128
  float* sums3 = inv2 + 128;         // 192
  float* mu3   = sums3 + 192;        // 96
  float* inv3  = mu3 + 96;           // 96
  int* counts  = (int*)(stats + 1152);
  int* cursor  = counts + 2048;
  int* rs      = cursor + 2048;      // 2049
  int* csr     = rs + 2049;          // E

  int eb = (E+255)/256;

  // CSR build (keyed by dst)
  k_zero_i<<<8,256,0,stream>>>(counts, 2048);
  k_zero_f<<<5,256,0,stream>>>(stats, 1152);
  k_count<<<eb,256,0,stream>>>(dst, E, counts);
  k_scan<<<1,256,0,stream>>>(counts, rs, cursor);
  k_fill<<<eb,256,0,stream>>>(dst, E, cursor, csr);

  // GAT layer 1
  k_feat<4,false><<<2048,256,0,stream>>>(x, W1, nullptr,nullptr,nullptr,nullptr, feat);
  k_elr<<<16384,256,0,stream>>>(feat, al1, ar1, el1, er1);
  k_gat_agg<4><<<2048,256,0,stream>>>(feat, el1, er1, rs, csr, src, b1, x1);

  // LN1 stats (apply fused into k_feat<8,true>)
  k_ln_part<<<512,256,0,stream>>>(x1, 8, sums1);
  k_ln_fin<<<1,256,0,stream>>>(sums1, mu1, inv1, 64);

  // GAT layer 2
  k_feat<8,true><<<4096,256,0,stream>>>(x1, W2, mu1, inv1, ln1w, ln1b, feat);
  k_elr<<<32768,256,0,stream>>>(feat, al2, ar2, el2, er2);
  k_gat_agg<8><<<2048,256,0,stream>>>(feat, el2, er2, rs, csr, src, b2, x2);

  // LN2 stats (apply fused into conv1)
  k_ln_part<<<1024,256,0,stream>>>(x2, 16, sums2);
  k_ln_fin<<<1,256,0,stream>>>(sums2, mu2, inv2, 128);

  // tc1 (5-tap, 16 -> 12) as MFMA GEMM, LN2 fused
  k_convT<16,12,5><<<1536,256,0,stream>>>(x2, mu2, inv2, ln2w, ln2b, tc1w, tc1b, xt1);

  // LN3 stats (apply fused into tc2)
  k_ln_part<<<768,256,0,stream>>>(xt1, 12, sums3);
  k_ln_fin<<<1,256,0,stream>>>(sums3, mu3, inv3, 96);

  // tc2 (1x1) as MFMA GEMM, LN3 fused
  k_convT<12,12,1><<<1536,256,0,stream>>>(xt1, mu3, inv3, ln3w, ln3b, tc2w, tc2b, xt2);

  // final fc
  k_fc<<<256,256,0,stream>>>(xt2, fcw, fcb, (float*)d_out);
}

// Round 3
// 255.979 us; speedup vs baseline: 2.3247x; 1.4919x over previous
//
#include <hip/hip_runtime.h>
#include <math.h>

#define NN 2048
#define BB 8
#define HH 2
#define NEG 0.2f
#define EPSL 1e-5f

typedef short bf16x8 __attribute__((ext_vector_type(8)));
typedef float f32x4 __attribute__((ext_vector_type(4)));

__device__ __forceinline__ float wave_reduce_sum(float v){
#pragma unroll
  for (int m = 32; m > 0; m >>= 1) v += __shfl_xor(v, m, 64);
  return v;
}

__device__ __forceinline__ unsigned short f2b(float f){
  union { float f; unsigned u; } v; v.f = f;
  unsigned r = v.u + 0x7FFFu + ((v.u >> 16) & 1u);
  return (unsigned short)(r >> 16);
}
__device__ __forceinline__ float b2f(unsigned short u){
  union { unsigned u; float f; } v; v.u = ((unsigned)u) << 16; return v.f;
}

__global__ void k_zero_f(float* p, int n){ int i = blockIdx.x*256+threadIdx.x; if(i<n) p[i]=0.f; }
__global__ void k_zero_i(int* p, int n){ int i = blockIdx.x*256+threadIdx.x; if(i<n) p[i]=0; }

__global__ void k_count(const int* __restrict__ dst, int E, int* cnt){
  int i = blockIdx.x*256+threadIdx.x; if(i<E) atomicAdd(&cnt[dst[i]],1);
}

// single block, 256 threads: exclusive scan of 2048 counts
__global__ void k_scan(const int* __restrict__ cnt, int* row_start, int* cursor){
  __shared__ int part[256];
  int tid = threadIdx.x;
  int loc[8]; int s = 0;
#pragma unroll
  for(int j=0;j<8;j++){ loc[j]=s; s += cnt[tid*8+j]; }
  part[tid]=s; __syncthreads();
  for(int off=1; off<256; off<<=1){
    int v = (tid>=off)? part[tid-off] : 0;
    __syncthreads();
    part[tid] += v;
    __syncthreads();
  }
  int excl = (tid==0)? 0 : part[tid-1];
#pragma unroll
  for(int j=0;j<8;j++){ int v=excl+loc[j]; row_start[tid*8+j]=v; cursor[tid*8+j]=v; }
  if(tid==255) row_start[2048]=excl+s;
}

// store src node id directly (removes one indirection in gat_agg)
__global__ void k_fill(const int* __restrict__ dst, const int* __restrict__ src,
                       int E, int* cursor, int* csrsrc){
  int i = blockIdx.x*256+threadIdx.x;
  if(i<E){ int p = atomicAdd(&cursor[dst[i]],1); csrsrc[p]=src[i]; }
}

// wlr[k*4+q]: q=0,1 -> sum_c W[k][h*64+c]*al[h][c] (h=q); q=2,3 -> ar version
__global__ void k_fold(const float* __restrict__ W, const float* __restrict__ al,
                       const float* __restrict__ ar, float* __restrict__ wlr){
  int tid = threadIdx.x;
  int k = tid>>2; int q = tid&3; int h = q&1;
  const float* av = (q>>1)? ar : al;
  float s = 0.f;
  for(int c=0;c<64;c++) s += W[k*128 + h*64 + c]*av[h*64+c];
  wlr[tid] = s;
}

// MFMA feat GEMM: feat[row][128] = LN(X)[row][64] * W[64][128]  (bf16 out)
// + el/er via 4 folded columns (wlr). 64 rows/block, 4 waves x 16 rows.
template<int TT, bool LN, bool BF16IN>
__global__ __launch_bounds__(256) void k_featm(
  const void* __restrict__ Xv, const float* __restrict__ W, const float* __restrict__ wlr,
  const float* __restrict__ mu, const float* __restrict__ inv,
  const float* __restrict__ lnw, const float* __restrict__ lnb,
  unsigned short* __restrict__ feat, float* __restrict__ el, float* __restrict__ er)
{
  __shared__ unsigned short xs[64*72];    // [row][k], pad 72
  __shared__ unsigned short wt[144*72];   // [co][k]; rows 128..131 = wlr, 132..143 unused
  int tid = threadIdx.x;
  int r0 = blockIdx.x*64;
  for(int idx=tid; idx<8192; idx+=256){ int k=idx>>7, co=idx&127; wt[co*72+k]=f2b(W[idx]); }
  { int q=tid&3, k=tid>>2; wt[(128+q)*72+k]=f2b(wlr[tid]); }
  for(int idx=tid; idx<1024; idx+=256){
    int rl = idx>>4, c4 = (idx&15)*4; int row = r0+rl;
    float v0,v1,v2,v3;
    if constexpr (BF16IN){
      const unsigned short* xp = (const unsigned short*)Xv + (size_t)row*64 + c4;
      uint2 u = *(const uint2*)xp;
      v0=b2f((unsigned short)(u.x&0xffff)); v1=b2f((unsigned short)(u.x>>16));
      v2=b2f((unsigned short)(u.y&0xffff)); v3=b2f((unsigned short)(u.y>>16));
    } else {
      float4 v = *(const float4*)((const float*)Xv + (size_t)row*64 + c4);
      v0=v.x; v1=v.y; v2=v.z; v3=v.w;
    }
    if constexpr (LN){
      int t = row%TT; int n_ = (row/TT)%NN; int b = row/(TT*NN); int g = b*TT+t;
      float m_ = mu[g], iv = inv[g];
      v0 = (v0-m_)*iv*lnw[n_*64+c4+0] + lnb[n_*64+c4+0];
      v1 = (v1-m_)*iv*lnw[n_*64+c4+1] + lnb[n_*64+c4+1];
      v2 = (v2-m_)*iv*lnw[n_*64+c4+2] + lnb[n_*64+c4+2];
      v3 = (v3-m_)*iv*lnw[n_*64+c4+3] + lnb[n_*64+c4+3];
    }
    unsigned short* p = &xs[rl*72 + c4];
    p[0]=f2b(v0); p[1]=f2b(v1); p[2]=f2b(v2); p[3]=f2b(v3);
  }
  __syncthreads();

  int w = tid>>6, lane = tid&63, lhi = lane>>4, llo = lane&15;
  f32x4 acc[8]; f32x4 accE = (f32x4){0.f,0.f,0.f,0.f};
#pragma unroll
  for(int ct=0;ct<8;ct++) acc[ct] = (f32x4){0.f,0.f,0.f,0.f};
#pragma unroll
  for(int s=0;s<2;s++){
    bf16x8 a = *(const bf16x8*)&xs[(w*16+llo)*72 + s*32 + lhi*8];
#pragma unroll
    for(int ct=0;ct<8;ct++){
      bf16x8 bfr = *(const bf16x8*)&wt[(ct*16+llo)*72 + s*32 + lhi*8];
      acc[ct] = __builtin_amdgcn_mfma_f32_16x16x32_bf16(a, bfr, acc[ct], 0,0,0);
    }
    bf16x8 be = *(const bf16x8*)&wt[(128+llo)*72 + s*32 + lhi*8];
    accE = __builtin_amdgcn_mfma_f32_16x16x32_bf16(a, be, accE, 0,0,0);
  }
#pragma unroll
  for(int ct=0;ct<8;ct++){
#pragma unroll
    for(int i=0;i<4;i++){
      int row = r0 + w*16 + lhi*4 + i;
      feat[(size_t)row*128 + ct*16 + llo] = f2b(acc[ct][i]);
    }
  }
  if(llo<4){
#pragma unroll
    for(int i=0;i<4;i++){
      int row = r0 + w*16 + lhi*4 + i;
      float v = accE[i];
      if(llo<2) el[row*2+llo] = v; else er[row*2+(llo-2)] = v;
    }
  }
}

// one block per dst node: online softmax + gather-aggregate + bias + relu (bf16 feat/out)
template<int TT>
__global__ __launch_bounds__(256) void k_gat_agg(
  const unsigned short* __restrict__ feat, const float* __restrict__ el, const float* __restrict__ er,
  const int* __restrict__ row_start, const int* __restrict__ csrsrc,
  const float* __restrict__ bias, unsigned int* __restrict__ out)
{
  constexpr int BTH = BB*TT*HH;     // 64 or 128
  constexpr int NP = BTH/8;         // channel-pair accs per thread
  int n = blockIdx.x; int tid = threadIdx.x;
  int beg = row_start[n]; int deg = row_start[n+1]-beg;
  __shared__ float m_s[BTH], s_s[BTH], er_s[BTH];
  __shared__ int src_s[16];
  __shared__ float alpha_s[16][BTH];
  int ebase = 0;
  if(tid < BTH){
    int h = tid&1; int t = (tid>>1)%TT; int b = tid/(2*TT);
    ebase = ((b*NN)*TT + t)*2 + h;
    float ern = er[ebase + n*TT*2];
    float m = -3.0e38f, s = 0.f;
    for(int j=0;j<deg;j++){
      int sn = csrsrc[beg+j];
      float e = el[ebase + sn*TT*2] + ern;
      e = e>0.f? e : NEG*e;
      float mn = fmaxf(m,e);
      s = s*__expf(m-mn) + __expf(e-mn);
      m = mn;
    }
    m_s[tid]=m; s_s[tid]=s; er_s[tid]=ern;
  }
  float2 acc[NP];
  int foff[NP];
  int c2 = (tid&31)*2; int rgrp = tid>>5;
#pragma unroll
  for(int a=0;a<NP;a++){
    int rr = rgrp + a*8;
    int h = rr&1; int t=(rr>>1)%TT; int b = rr/(2*TT);
    foff[a] = ((b*NN)*TT + t)*128 + h*64 + c2;
    acc[a].x=0.f; acc[a].y=0.f;
  }
  __syncthreads();
  for(int c0=0;c0<deg;c0+=16){
    int cl = min(16, deg-c0);
    if(tid<cl) src_s[tid] = csrsrc[beg+c0+tid];
    __syncthreads();
    if(tid<BTH){
      float m = m_s[tid]; float sinv = 1.f/s_s[tid]; float ern = er_s[tid];
      for(int j=0;j<cl;j++){
        int sn = src_s[j];
        float e = el[ebase + sn*TT*2] + ern;
        e = e>0.f? e : NEG*e;
        alpha_s[j][tid] = __expf(e-m)*sinv;
      }
    }
    __syncthreads();
    for(int j=0;j<cl;j++){
      size_t base = (size_t)src_s[j]*(TT*128);
#pragma unroll
      for(int a=0;a<NP;a++){
        unsigned u = *(const unsigned*)&feat[base + foff[a]];
        float al_ = alpha_s[j][rgrp + a*8];
        acc[a].x += al_*b2f((unsigned short)(u&0xffff));
        acc[a].y += al_*b2f((unsigned short)(u>>16));
      }
    }
    __syncthreads();
  }
#pragma unroll
  for(int a=0;a<NP;a++){
    int rr = rgrp + a*8;
    int h = rr&1; int t=(rr>>1)%TT; int b = rr/(2*TT);
    float v0 = fmaxf(acc[a].x + bias[h*64+c2], 0.f);
    float v1 = fmaxf(acc[a].y + bias[h*64+c2+1], 0.f);
    unsigned pack = (unsigned)f2b(v0) | ((unsigned)f2b(v1)<<16);
    out[(((size_t)b*NN + n)*(TT*2) + (t*2+h))*32 + (c2>>1)] = pack;
  }
}

// partial sums for LN over (N,C) per group g=(b,tg). X (bf16) layout [B,N,Tg,64]. 8 splits.
__global__ __launch_bounds__(256) void k_ln_part(const unsigned short* __restrict__ X, int Tg, float* __restrict__ sums)
{
  int g = blockIdx.x >> 3;
  int sp = blockIdx.x & 7;
  int b = g / Tg; int tg = g % Tg;
  size_t base = ((size_t)b*NN*Tg + tg)*64;
  int c = threadIdx.x & 63; int nsub = threadIdx.x>>6;
  float s=0.f, q=0.f;
  int n0 = sp*256;
  for(int k=0;k<64;k++){
    int n_ = n0 + nsub + k*4;
    float v = b2f(X[base + (size_t)n_*(Tg*64) + c]);
    s += v; q += v*v;
  }
  s = wave_reduce_sum(s); q = wave_reduce_sum(q);
  __shared__ float red[8];
  int wid = threadIdx.x>>6; int lane = threadIdx.x&63;
  if(lane==0){ red[wid*2]=s; red[wid*2+1]=q; }
  __syncthreads();
  if(threadIdx.x==0){
    float S=0.f,Q=0.f;
    for(int w=0;w<4;w++){ S+=red[w*2]; Q+=red[w*2+1]; }
    atomicAdd(&sums[g*2], S); atomicAdd(&sums[g*2+1], Q);
  }
}

__global__ void k_ln_fin(const float* __restrict__ sums, float* __restrict__ mu, float* __restrict__ inv, int G){
  int g = threadIdx.x + blockIdx.x*256;
  if(g<G){
    float cnt = (float)(NN*64);
    float m = sums[g*2]/cnt;
    float v = sums[g*2+1]/cnt - m*m;
    mu[g]=m; inv[g]=rsqrtf(v+EPSL);
  }
}

// Temporal conv as MFMA GEMM, LN fused on (bf16) input load, bf16 out.
template<int TIN, int TOUT, int KT>
__global__ __launch_bounds__(256) void k_convT(
  const unsigned short* __restrict__ xin,   // [BN][TIN][64] bf16
  const float* __restrict__ mu, const float* __restrict__ inv,
  const float* __restrict__ lnw, const float* __restrict__ lnb,
  const float* __restrict__ w,     // [co][ci][1][KT]
  const float* __restrict__ bias,
  unsigned short* __restrict__ y)  // [BN][TOUT][64] bf16
{
  constexpr int K = KT*64;
  constexpr int KSTEPS = K/32;
  constexpr int KPAD = K + 24;
  constexpr int XPAD = 88;
  constexpr int XN = TIN*XPAD + 8;
  constexpr int NODES = 12;
  __shared__ __align__(16) unsigned short xs[NODES*XN];
  __shared__ __align__(16) unsigned short wt[64*KPAD];
  int tid = threadIdx.x;
  int r0 = blockIdx.x*128;
  int bn0 = r0/TOUT;

  for(int idx = tid; idx < 64*K; idx += 256){
    int co = idx/K; int kap = idx - co*K;
    int ktap = kap >> 6; int ci = kap & 63;
    wt[co*KPAD + kap] = f2b(w[(co*64+ci)*KT + ktap]);
  }
  for(int idx = tid; idx < NODES*TIN*16; idx += 256){
    int nd = idx/(TIN*16); int rem = idx - nd*(TIN*16);
    int t = rem>>4; int c4 = (rem&15)*4;
    int bn = bn0+nd;
    if(bn < 16384){
      int b = bn>>11; int n_ = bn&2047; int g = b*TIN+t;
      uint2 u = *(const uint2*)&xin[((size_t)bn*TIN+t)*64 + c4];
      float v0=b2f((unsigned short)(u.x&0xffff)), v1=b2f((unsigned short)(u.x>>16));
      float v2=b2f((unsigned short)(u.y&0xffff)), v3=b2f((unsigned short)(u.y>>16));
      float m_ = mu[g], iv = inv[g];
      unsigned short* p = &xs[nd*XN + t*XPAD + c4];
      p[0]=f2b((v0-m_)*iv*lnw[n_*64+c4+0]+lnb[n_*64+c4+0]);
      p[1]=f2b((v1-m_)*iv*lnw[n_*64+c4+1]+lnb[n_*64+c4+1]);
      p[2]=f2b((v2-m_)*iv*lnw[n_*64+c4+2]+lnb[n_*64+c4+2]);
      p[3]=f2b((v3-m_)*iv*lnw[n_*64+c4+3]+lnb[n_*64+c4+3]);
    }
  }
  __syncthreads();

  int wv_ = tid>>6; int lane = tid&63;
  int lhi = lane>>4; int llo = lane&15;
  int nodeA[2], tA[2];
#pragma unroll
  for(int rt=0; rt<2; rt++){
    int r = r0 + wv_*32 + rt*16 + llo;
    int nd = r/TOUT;
    nodeA[rt] = nd - bn0; tA[rt] = r - nd*TOUT;
  }
  f32x4 acc[2][4];
#pragma unroll
  for(int i=0;i<2;i++)
#pragma unroll
    for(int j=0;j<4;j++) acc[i][j] = (f32x4){0.f,0.f,0.f,0.f};

#pragma unroll
  for(int s=0; s<KSTEPS; s++){
    int ktap = s>>1; int cib = ((s&1)<<5) + lhi*8;
    bf16x8 a0 = *(const bf16x8*)&xs[nodeA[0]*XN + (tA[0]+ktap)*XPAD + cib];
    bf16x8 a1 = *(const bf16x8*)&xs[nodeA[1]*XN + (tA[1]+ktap)*XPAD + cib];
    int kb = s*32 + lhi*8;
#pragma unroll
    for(int ct=0; ct<4; ct++){
      bf16x8 bfr = *(const bf16x8*)&wt[(ct*16+llo)*KPAD + kb];
      acc[0][ct] = __builtin_amdgcn_mfma_f32_16x16x32_bf16(a0, bfr, acc[0][ct], 0,0,0);
      acc[1][ct] = __builtin_amdgcn_mfma_f32_16x16x32_bf16(a1, bfr, acc[1][ct], 0,0,0);
    }
  }
#pragma unroll
  for(int rt=0; rt<2; rt++){
    int rbase = r0 + wv_*32 + rt*16 + lhi*4;
#pragma unroll
    for(int ct=0; ct<4; ct++){
      int co = ct*16 + llo;
      float bb = bias[co];
#pragma unroll
      for(int i=0;i<4;i++){
        y[(size_t)(rbase+i)*64 + co] = f2b(acc[rt][ct][i] + bb);
      }
    }
  }
}

// final fc on bf16 xt2; out fp32.
__global__ __launch_bounds__(256) void k_fc(const unsigned short* __restrict__ xt2,
  const float* __restrict__ fw, const float* __restrict__ fb, float* __restrict__ out)
{
  __shared__ float fws[12][772];
  __shared__ float ch[8][768];
  int tid = threadIdx.x;
  int b = blockIdx.x>>5; int nh = blockIdx.x&31;
  for(int i=tid;i<9216;i+=256){ fws[i/768][i%768] = fw[i]; }
  float acc[3]; int cidx[3], oidx[3];
#pragma unroll
  for(int k=0;k<3;k++){ int oi = tid + k*256; cidx[k]=oi/12; oidx[k]=oi%12; acc[k]=0.f; }
  for(int c0=0;c0<64;c0+=8){
    __syncthreads();
    for(int i=tid;i<6144;i+=256){
      int nl = i/768; int r = i%768;
      ch[nl][r] = b2f(xt2[((size_t)(b*2048 + nh*64 + c0+nl))*768 + r]);
    }
    __syncthreads();
    for(int nl=0;nl<8;nl++){
#pragma unroll
      for(int t=0;t<12;t++){
#pragma unroll
        for(int k=0;k<3;k++){
          acc[k] += ch[nl][t*64 + cidx[k]] * fws[oidx[k]][(c0+nl)*12 + t];
        }
      }
    }
  }
#pragma unroll
  for(int k=0;k<3;k++){
    int nprime = cidx[k]*32 + nh;
    out[((size_t)b*2048 + nprime)*12 + oidx[k]] = acc[k] + fb[oidx[k]];
  }
}

extern "C" void kernel_launch(void* const* d_in, const int* in_sizes, int n_in,
                              void* d_out, int out_size, void* d_ws, size_t ws_size,
                              hipStream_t stream) {
  (void)n_in; (void)out_size; (void)ws_size;
  const float* x    = (const float*)d_in[0];
  const int*   src  = (const int*)d_in[1];
  const int*   dst  = (const int*)d_in[2];
  const float* W1   = (const float*)d_in[3];
  const float* al1  = (const float*)d_in[4];
  const float* ar1  = (const float*)d_in[5];
  const float* b1   = (const float*)d_in[6];
  const float* W2   = (const float*)d_in[7];
  const float* al2  = (const float*)d_in[8];
  const float* ar2  = (const float*)d_in[9];
  const float* b2   = (const float*)d_in[10];
  const float* ln1w = (const float*)d_in[11];
  const float* ln1b = (const float*)d_in[12];
  const float* ln2w = (const float*)d_in[13];
  const float* ln2b = (const float*)d_in[14];
  const float* tc1w = (const float*)d_in[15];
  const float* tc1b = (const float*)d_in[16];
  const float* ln3w = (const float*)d_in[17];
  const float* ln3b = (const float*)d_in[18];
  const float* tc2w = (const float*)d_in[19];
  const float* tc2b = (const float*)d_in[20];
  const float* fcw  = (const float*)d_in[21];
  const float* fcb  = (const float*)d_in[22];
  int E = in_sizes[1];

  unsigned short* U = (unsigned short*)d_ws;
  unsigned short* feat = U + 0;            // 16,777,216 (layer1 uses first 8.39M)
  unsigned short* x1   = U + 16777216;     // 8,388,608
  unsigned short* x2   = U + 25165824;     // 16,777,216
  unsigned short* xt1  = U + 0;            // 12,582,912 (reuse feat after GAT2)
  unsigned short* xt2  = U + 12582912;     // 12,582,912 (overlaps dead x1)
  float* F = (float*)(U + 41943040);
  float* el1 = F;                // 131072
  float* er1 = el1 + 131072;     // 131072
  float* el2 = er1 + 131072;     // 262144
  float* er2 = el2 + 262144;     // 262144
  float* wlr1 = er2 + 262144;    // 256
  float* wlr2 = wlr1 + 256;      // 256
  float* stats = wlr2 + 256;     // 1152
  float* sums1 = stats;          // 128
  float* mu1   = sums1 + 128;    // 64
  float* inv1  = mu1 + 64;       // 64
  float* sums2 = inv1 + 64;      // 256
  float* mu2   = sums2 + 256;    // 128
  float* inv2  = mu2 + 128;      // 128
  float* sums3 = inv2 + 128;     // 192
  float* mu3   = sums3 + 192;    // 96
  float* inv3  = mu3 + 96;       // 96
  int* counts  = (int*)(stats + 1152);
  int* cursor  = counts + 2048;
  int* rs      = cursor + 2048;  // 2049
  int* csrsrc  = rs + 2049;      // E

  int eb = (E+255)/256;

  // CSR build (keyed by dst, storing src ids)
  k_zero_i<<<8,256,0,stream>>>(counts, 2048);
  k_zero_f<<<5,256,0,stream>>>(stats, 1152);
  k_count<<<eb,256,0,stream>>>(dst, E, counts);
  k_scan<<<1,256,0,stream>>>(counts, rs, cursor);
  k_fill<<<eb,256,0,stream>>>(dst, src, E, cursor, csrsrc);

  // fold al/ar into GEMM columns
  k_fold<<<1,256,0,stream>>>(W1, al1, ar1, wlr1);
  k_fold<<<1,256,0,stream>>>(W2, al2, ar2, wlr2);

  // GAT layer 1
  k_featm<4,false,false><<<1024,256,0,stream>>>(x, W1, wlr1, nullptr,nullptr,nullptr,nullptr, feat, el1, er1);
  k_gat_agg<4><<<2048,256,0,stream>>>(feat, el1, er1, rs, csrsrc, b1, (unsigned int*)x1);

  // LN1 stats (apply fused into k_featm layer2)
  k_ln_part<<<512,256,0,stream>>>(x1, 8, sums1);
  k_ln_fin<<<1,256,0,stream>>>(sums1, mu1, inv1, 64);

  // GAT layer 2
  k_featm<8,true,true><<<2048,256,0,stream>>>(x1, W2, wlr2, mu1, inv1, ln1w, ln1b, feat, el2, er2);
  k_gat_agg<8><<<2048,256,0,stream>>>(feat, el2, er2, rs, csrsrc, b2, (unsigned int*)x2);

  // LN2 stats (apply fused into conv1)
  k_ln_part<<<1024,256,0,stream>>>(x2, 16, sums2);
  k_ln_fin<<<1,256,0,stream>>>(sums2, mu2, inv2, 128);

  // tc1 (5-tap, 16 -> 12) as MFMA GEMM, LN2 fused
  k_convT<16,12,5><<<1536,256,0,stream>>>(x2, mu2, inv2, ln2w, ln2b, tc1w, tc1b, xt1);

  // LN3 stats (apply fused into tc2)
  k_ln_part<<<768,256,0,stream>>>(xt1, 12, sums3);
  k_ln_fin<<<1,256,0,stream>>>(sums3, mu3, inv3, 96);

  // tc2 (1x1) as MFMA GEMM, LN3 fused
  k_convT<12,12,1><<<1536,256,0,stream>>>(xt1, mu3, inv3, ln3w, ln3b, tc2w, tc2b, xt2);

  // final fc
  k_fc<<<256,256,0,stream>>>(xt2, fcw, fcb, (float*)d_out);
}

// Round 4
// 249.176 us; speedup vs baseline: 2.3882x; 1.0273x over previous
//
#include <hip/hip_runtime.h>
#include <math.h>

#define NN 2048
#define BB 8
#define HH 2
#define NEG 0.2f
#define EPSL 1e-5f

typedef short bf16x8 __attribute__((ext_vector_type(8)));
typedef float f32x4 __attribute__((ext_vector_type(4)));

__device__ __forceinline__ float wave_reduce_sum(float v){
#pragma unroll
  for (int m = 32; m > 0; m >>= 1) v += __shfl_xor(v, m, 64);
  return v;
}

__device__ __forceinline__ unsigned short f2b(float f){
  union { float f; unsigned u; } v; v.f = f;
  unsigned r = v.u + 0x7FFFu + ((v.u >> 16) & 1u);
  return (unsigned short)(r >> 16);
}
__device__ __forceinline__ float b2f(unsigned short u){
  union { unsigned u; float f; } v; v.u = ((unsigned)u) << 16; return v.f;
}

__global__ void k_count(const int* __restrict__ dst, int E, int* cnt){
  int i = blockIdx.x*256+threadIdx.x; if(i<E) atomicAdd(&cnt[dst[i]],1);
}

__global__ void k_scan(const int* __restrict__ cnt, int* row_start, int* cursor){
  __shared__ int part[256];
  int tid = threadIdx.x;
  int loc[8]; int s = 0;
#pragma unroll
  for(int j=0;j<8;j++){ loc[j]=s; s += cnt[tid*8+j]; }
  part[tid]=s; __syncthreads();
  for(int off=1; off<256; off<<=1){
    int v = (tid>=off)? part[tid-off] : 0;
    __syncthreads();
    part[tid] += v;
    __syncthreads();
  }
  int excl = (tid==0)? 0 : part[tid-1];
#pragma unroll
  for(int j=0;j<8;j++){ int v=excl+loc[j]; row_start[tid*8+j]=v; cursor[tid*8+j]=v; }
  if(tid==255) row_start[2048]=excl+s;
}

__global__ void k_fill(const int* __restrict__ dst, const int* __restrict__ src,
                       int E, int* cursor, int* csrsrc){
  int i = blockIdx.x*256+threadIdx.x;
  if(i<E){ int p = atomicAdd(&cursor[dst[i]],1); csrsrc[p]=src[i]; }
}

// one-shot weight prep: bf16 images in final staging layouts + zero counts
__global__ void k_prep(const float* __restrict__ W1, const float* __restrict__ al1, const float* __restrict__ ar1,
                       const float* __restrict__ W2, const float* __restrict__ al2, const float* __restrict__ ar2,
                       const float* __restrict__ tc1w, const float* __restrict__ tc2w,
                       unsigned short* wf1, unsigned short* wf2,
                       unsigned short* wc1, unsigned short* wc2, int* counts){
  int blk = blockIdx.x; int tid = threadIdx.x;
  if(blk==0){ for(int i=tid;i<8192;i+=256){ int k=i>>7, co=i&127; wf1[co*72+k]=f2b(W1[i]); } }
  else if(blk==1){ for(int i=tid;i<8192;i+=256){ int k=i>>7, co=i&127; wf2[co*72+k]=f2b(W2[i]); } }
  else if(blk==2){
    int k=tid>>2, q=tid&3, h=q&1;
    { const float* av=(q>>1)?ar1:al1; float s=0.f;
      for(int c=0;c<64;c++) s+=W1[k*128+h*64+c]*av[h*64+c];
      wf1[(128+q)*72+k]=f2b(s); }
    { const float* av=(q>>1)?ar2:al2; float s=0.f;
      for(int c=0;c<64;c++) s+=W2[k*128+h*64+c]*av[h*64+c];
      wf2[(128+q)*72+k]=f2b(s); }
  }
  else if(blk==3){
    for(int co=0;co<64;co++)
      for(int kap=tid;kap<320;kap+=256){
        int kt=kap>>6, ci=kap&63;
        wc1[co*320+kap]=f2b(tc1w[(co*64+ci)*5+kt]);
      }
  }
  else if(blk==4){ for(int i=tid;i<4096;i+=256) wc2[i]=f2b(tc2w[i]); }
  else { for(int i=tid;i<2048;i+=256) counts[i]=0; }
}

// MFMA feat GEMM, node-major outputs:
// feat2[((n*TT+t)*8+b)*128 + d], el2/er2[((n*TT+t)*8+b)*2 + h]
template<int TT, int LT, bool LN, bool BF16IN>
__global__ __launch_bounds__(256) void k_featm(
  const void* __restrict__ Xv, const unsigned short* __restrict__ wf,
  const float* __restrict__ mu, const float* __restrict__ inv,
  const float* __restrict__ lnw, const float* __restrict__ lnb,
  unsigned short* __restrict__ feat, float* __restrict__ el, float* __restrict__ er)
{
  __shared__ __align__(16) unsigned short xs[64*72];
  __shared__ __align__(16) unsigned short wt[144*72];
  int tid = threadIdx.x;
  int r0 = blockIdx.x*64;
  for(int i=tid;i<1296;i+=256) ((uint4*)wt)[i] = ((const uint4*)wf)[i];
  for(int idx=tid; idx<1024; idx+=256){
    int rl = idx>>4, c4 = (idx&15)*4; int row = r0+rl;
    float v0,v1,v2,v3;
    if constexpr (BF16IN){
      uint2 u = *(const uint2*)((const unsigned short*)Xv + (size_t)row*64 + c4);
      v0=b2f((unsigned short)(u.x&0xffff)); v1=b2f((unsigned short)(u.x>>16));
      v2=b2f((unsigned short)(u.y&0xffff)); v3=b2f((unsigned short)(u.y>>16));
    } else {
      float4 v = *(const float4*)((const float*)Xv + (size_t)row*64 + c4);
      v0=v.x; v1=v.y; v2=v.z; v3=v.w;
    }
    if constexpr (LN){
      int t = row&(TT-1); int n_ = (row>>LT)&2047; int b = row>>(LT+11); int g = b*TT+t;
      float m_ = mu[g], iv = inv[g];
      v0 = (v0-m_)*iv*lnw[n_*64+c4+0] + lnb[n_*64+c4+0];
      v1 = (v1-m_)*iv*lnw[n_*64+c4+1] + lnb[n_*64+c4+1];
      v2 = (v2-m_)*iv*lnw[n_*64+c4+2] + lnb[n_*64+c4+2];
      v3 = (v3-m_)*iv*lnw[n_*64+c4+3] + lnb[n_*64+c4+3];
    }
    unsigned short* p = &xs[rl*72 + c4];
    p[0]=f2b(v0); p[1]=f2b(v1); p[2]=f2b(v2); p[3]=f2b(v3);
  }
  __syncthreads();

  int w = tid>>6, lane = tid&63, lhi = lane>>4, llo = lane&15;
  f32x4 acc[8]; f32x4 accE = (f32x4){0.f,0.f,0.f,0.f};
#pragma unroll
  for(int ct=0;ct<8;ct++) acc[ct] = (f32x4){0.f,0.f,0.f,0.f};
#pragma unroll
  for(int s=0;s<2;s++){
    bf16x8 a = *(const bf16x8*)&xs[(w*16+llo)*72 + s*32 + lhi*8];
#pragma unroll
    for(int ct=0;ct<8;ct++){
      bf16x8 bfr = *(const bf16x8*)&wt[(ct*16+llo)*72 + s*32 + lhi*8];
      acc[ct] = __builtin_amdgcn_mfma_f32_16x16x32_bf16(a, bfr, acc[ct], 0,0,0);
    }
    bf16x8 be = *(const bf16x8*)&wt[(128+llo)*72 + s*32 + lhi*8];
    accE = __builtin_amdgcn_mfma_f32_16x16x32_bf16(a, be, accE, 0,0,0);
  }
#pragma unroll
  for(int i=0;i<4;i++){
    int row = r0 + w*16 + lhi*4 + i;
    int t = row&(TT-1); int n_ = (row>>LT)&2047; int b = row>>(LT+11);
    size_t base = ((size_t)(n_*TT+t)*8 + b)*128;
#pragma unroll
    for(int ct=0;ct<8;ct++) feat[base + ct*16 + llo] = f2b(acc[ct][i]);
    if(llo<4){
      int eb_ = (int)(base>>6);  // ((n*TT+t)*8+b)*2
      if(llo<2) el[eb_+llo] = accE[i]; else er[eb_+(llo-2)] = accE[i];
    }
  }
}

// one block per dst node: online softmax + gather + bias + relu + LN partial sums
template<int TT>
__global__ __launch_bounds__(256) void k_gat_agg(
  const unsigned short* __restrict__ feat, const float* __restrict__ el, const float* __restrict__ er,
  const int* __restrict__ row_start, const int* __restrict__ csrsrc,
  const float* __restrict__ bias, unsigned int* __restrict__ out, float2* __restrict__ pg)
{
  constexpr int BTH = BB*TT*HH;
  constexpr int NP = BTH/8;
  int n = blockIdx.x; int tid = threadIdx.x;
  int beg = row_start[n]; int deg = row_start[n+1]-beg;
  __shared__ float m_s[BTH], s_s[BTH], er_s[BTH];
  __shared__ int src_s[16];
  __shared__ float alpha_s[16][BTH];
  int ebase = 0;
  if(tid < BTH){
    int h = tid&1; int t = (tid>>1)%TT; int b = tid/(2*TT);
    ebase = (t*8+b)*2 + h;                       // node-major el/er
    float ern = er[n*(TT*16) + ebase];
    float m = -3.0e38f, s = 0.f;
    for(int j=0;j<deg;j++){
      int sn = csrsrc[beg+j];
      float e = el[sn*(TT*16) + ebase] + ern;
      e = e>0.f? e : NEG*e;
      float mn = fmaxf(m,e);
      s = s*__expf(m-mn) + __expf(e-mn);
      m = mn;
    }
    m_s[tid]=m; s_s[tid]=s; er_s[tid]=ern;
  }
  float2 acc[NP];
  int foff[NP];
  int c2 = (tid&31)*2; int rgrp = tid>>5;
#pragma unroll
  for(int a=0;a<NP;a++){
    int rr = rgrp + a*8;
    int h = rr&1; int t=(rr>>1)%TT; int b = rr/(2*TT);
    foff[a] = (t*8+b)*128 + h*64 + c2;
    acc[a].x=0.f; acc[a].y=0.f;
  }
  __syncthreads();
  for(int c0=0;c0<deg;c0+=16){
    int cl = min(16, deg-c0);
    if(tid<cl) src_s[tid] = csrsrc[beg+c0+tid];
    __syncthreads();
    if(tid<BTH){
      float m = m_s[tid]; float sinv = 1.f/s_s[tid]; float ern = er_s[tid];
      for(int j=0;j<cl;j++){
        int sn = src_s[j];
        float e = el[sn*(TT*16) + ebase] + ern;
        e = e>0.f? e : NEG*e;
        alpha_s[j][tid] = __expf(e-m)*sinv;
      }
    }
    __syncthreads();
    for(int j=0;j<cl;j++){
      size_t base = (size_t)src_s[j]*(TT*1024);   // contiguous per-edge chunk
#pragma unroll
      for(int a=0;a<NP;a++){
        unsigned u = *(const unsigned*)&feat[base + foff[a]];
        float al_ = alpha_s[j][rgrp + a*8];
        acc[a].x += al_*b2f((unsigned short)(u&0xffff));
        acc[a].y += al_*b2f((unsigned short)(u>>16));
      }
    }
    __syncthreads();
  }
#pragma unroll
  for(int a=0;a<NP;a++){
    int rr = rgrp + a*8;
    int h = rr&1; int t=(rr>>1)%TT; int b = rr/(2*TT);
    float v0 = fmaxf(acc[a].x + bias[h*64+c2], 0.f);
    float v1 = fmaxf(acc[a].y + bias[h*64+c2+1], 0.f);
    unsigned pack = (unsigned)f2b(v0) | ((unsigned)f2b(v1)<<16);
    out[(((size_t)b*NN + n)*(TT*2) + (t*2+h))*32 + (c2>>1)] = pack;
    float s = v0+v1, q = v0*v0+v1*v1;
#pragma unroll
    for(int mM=1;mM<=16;mM<<=1){ s += __shfl_xor(s,mM,64); q += __shfl_xor(q,mM,64); }
    if((tid&31)==0) pg[rr*2048 + n] = make_float2(s,q);
  }
}

// finalize LN stats from partials. mode0: pg[g][2048] contiguous (gat, remap groups by LT)
// mode1: pr rows bn*12+to (conv), g=(b,to)
__global__ void k_lnfin(const float2* __restrict__ p, float* __restrict__ mu, float* __restrict__ inv,
                        int mode, int LT){
  int g = blockIdx.x; int tid = threadIdx.x;
  int base, stride;
  if(mode==0){ base = g*2048; stride = 1; }
  else { int b = g/12; int to = g - b*12; base = b*2048*12 + to; stride = 12; }
  float s=0.f, q=0.f;
  for(int i=tid;i<2048;i+=256){ float2 v = p[base + i*stride]; s+=v.x; q+=v.y; }
  s = wave_reduce_sum(s); q = wave_reduce_sum(q);
  __shared__ float red[8];
  int wid=tid>>6, lane=tid&63;
  if(lane==0){ red[wid]=s; red[4+wid]=q; }
  __syncthreads();
  if(tid==0){
    float S=red[0]+red[1]+red[2]+red[3];
    float Q=red[4]+red[5]+red[6]+red[7];
    float cnt = 131072.f;
    float m = S/cnt; float var = Q/cnt - m*m;
    int gout;
    if(mode==0){ int h=g&1; int t=(g>>1)&((1<<LT)-1); int b=g>>(1+LT); gout = b*(2<<LT) + t*2 + h; }
    else gout = g;
    mu[gout]=m; inv[gout]=rsqrtf(var+EPSL);
  }
}

// Temporal conv as MFMA GEMM; B-fragments straight from prepped global (L2-resident);
// X (LN-applied, bf16) in LDS; optional per-row LN partial sums for the NEXT LN.
template<int TIN, int TOUT, int KT, bool PSUM>
__global__ __launch_bounds__(256) void k_convT(
  const unsigned short* __restrict__ xin,
  const float* __restrict__ mu, const float* __restrict__ inv,
  const float* __restrict__ lnw, const float* __restrict__ lnb,
  const unsigned short* __restrict__ wcg,   // [64][KT*64] bf16
  const float* __restrict__ bias,
  unsigned short* __restrict__ y, float2* __restrict__ pr)
{
  constexpr int K = KT*64;
  constexpr int KSTEPS = K/32;
  constexpr int XPAD = 72;
  constexpr int XN = TIN*XPAD + 8;
  constexpr int NODES = 12;
  __shared__ __align__(16) unsigned short xs[NODES*XN];
  int tid = threadIdx.x;
  int r0 = blockIdx.x*128;
  int bn0 = r0/TOUT;

  for(int idx = tid; idx < NODES*TIN*16; idx += 256){
    int nd = idx/(TIN*16); int rem = idx - nd*(TIN*16);
    int t = rem>>4; int c4 = (rem&15)*4;
    int bn = bn0+nd;
    if(bn < 16384){
      int b = bn>>11; int n_ = bn&2047; int g = b*TIN+t;
      uint2 u = *(const uint2*)&xin[((size_t)bn*TIN+t)*64 + c4];
      float v0=b2f((unsigned short)(u.x&0xffff)), v1=b2f((unsigned short)(u.x>>16));
      float v2=b2f((unsigned short)(u.y&0xffff)), v3=b2f((unsigned short)(u.y>>16));
      float m_ = mu[g], iv = inv[g];
      unsigned short* p = &xs[nd*XN + t*XPAD + c4];
      p[0]=f2b((v0-m_)*iv*lnw[n_*64+c4+0]+lnb[n_*64+c4+0]);
      p[1]=f2b((v1-m_)*iv*lnw[n_*64+c4+1]+lnb[n_*64+c4+1]);
      p[2]=f2b((v2-m_)*iv*lnw[n_*64+c4+2]+lnb[n_*64+c4+2]);
      p[3]=f2b((v3-m_)*iv*lnw[n_*64+c4+3]+lnb[n_*64+c4+3]);
    }
  }
  __syncthreads();

  int wv_ = tid>>6; int lane = tid&63;
  int lhi = lane>>4; int llo = lane&15;
  int nodeA[2], tA[2];
#pragma unroll
  for(int rt=0; rt<2; rt++){
    int r = r0 + wv_*32 + rt*16 + llo;
    int nd = r/TOUT;
    nodeA[rt] = nd - bn0; tA[rt] = r - nd*TOUT;
  }
  f32x4 acc[2][4];
#pragma unroll
  for(int i=0;i<2;i++)
#pragma unroll
    for(int j=0;j<4;j++) acc[i][j] = (f32x4){0.f,0.f,0.f,0.f};

#pragma unroll 2
  for(int s=0; s<KSTEPS; s++){
    int ktap = s>>1; int cib = ((s&1)<<5) + lhi*8;
    bf16x8 a0 = *(const bf16x8*)&xs[nodeA[0]*XN + (tA[0]+ktap)*XPAD + cib];
    bf16x8 a1 = *(const bf16x8*)&xs[nodeA[1]*XN + (tA[1]+ktap)*XPAD + cib];
    int kb = s*32 + lhi*8;
#pragma unroll
    for(int ct=0; ct<4; ct++){
      bf16x8 bfr = *(const bf16x8*)(wcg + (ct*16+llo)*K + kb);
      acc[0][ct] = __builtin_amdgcn_mfma_f32_16x16x32_bf16(a0, bfr, acc[0][ct], 0,0,0);
      acc[1][ct] = __builtin_amdgcn_mfma_f32_16x16x32_bf16(a1, bfr, acc[1][ct], 0,0,0);
    }
  }
#pragma unroll
  for(int rt=0; rt<2; rt++){
    int rbase = r0 + wv_*32 + rt*16 + lhi*4;
    float vs[4][4];
#pragma unroll
    for(int ct=0; ct<4; ct++){
      float bb = bias[ct*16+llo];
#pragma unroll
      for(int i=0;i<4;i++) vs[ct][i] = acc[rt][ct][i] + bb;
    }
#pragma unroll
    for(int ct=0; ct<4; ct++)
#pragma unroll
      for(int i=0;i<4;i++)
        y[(size_t)(rbase+i)*64 + ct*16+llo] = f2b(vs[ct][i]);
    if constexpr (PSUM){
#pragma unroll
      for(int i=0;i<4;i++){
        float s = vs[0][i]+vs[1][i]+vs[2][i]+vs[3][i];
        float q = vs[0][i]*vs[0][i]+vs[1][i]*vs[1][i]+vs[2][i]*vs[2][i]+vs[3][i]*vs[3][i];
#pragma unroll
        for(int mM=1;mM<=8;mM<<=1){ s += __shfl_xor(s,mM,64); q += __shfl_xor(q,mM,64); }
        if(llo==0) pr[rbase+i] = make_float2(s,q);
      }
    }
  }
}

// final fc on bf16 xt2; out fp32 (torch reshape = linear view of [B,C,N,12])
__global__ __launch_bounds__(256) void k_fc(const unsigned short* __restrict__ xt2,
  const float* __restrict__ fw, const float* __restrict__ fb, float* __restrict__ out)
{
  __shared__ float fws[12][772];
  __shared__ float ch[8][768];
  int tid = threadIdx.x;
  int b = blockIdx.x>>5; int nh = blockIdx.x&31;
  for(int i=tid;i<9216;i+=256){ fws[i/768][i%768] = fw[i]; }
  float acc[3]; int cidx[3], oidx[3];
#pragma unroll
  for(int k=0;k<3;k++){ int oi = tid + k*256; cidx[k]=oi/12; oidx[k]=oi%12; acc[k]=0.f; }
  for(int c0=0;c0<64;c0+=8){
    __syncthreads();
    for(int i=tid;i<6144;i+=256){
      int nl = i/768; int r = i%768;
      ch[nl][r] = b2f(xt2[((size_t)(b*2048 + nh*64 + c0+nl))*768 + r]);
    }
    __syncthreads();
    for(int nl=0;nl<8;nl++){
#pragma unroll
      for(int t=0;t<12;t++){
#pragma unroll
        for(int k=0;k<3;k++){
          acc[k] += ch[nl][t*64 + cidx[k]] * fws[oidx[k]][(c0+nl)*12 + t];
        }
      }
    }
  }
#pragma unroll
  for(int k=0;k<3;k++){
    int nprime = cidx[k]*32 + nh;
    out[((size_t)b*2048 + nprime)*12 + oidx[k]] = acc[k] + fb[oidx[k]];
  }
}

extern "C" void kernel_launch(void* const* d_in, const int* in_sizes, int n_in,
                              void* d_out, int out_size, void* d_ws, size_t ws_size,
                              hipStream_t stream) {
  (void)n_in; (void)out_size; (void)ws_size;
  const float* x    = (const float*)d_in[0];
  const int*   src  = (const int*)d_in[1];
  const int*   dst  = (const int*)d_in[2];
  const float* W1   = (const float*)d_in[3];
  const float* al1  = (const float*)d_in[4];
  const float* ar1  = (const float*)d_in[5];
  const float* b1   = (const float*)d_in[6];
  const float* W2   = (const float*)d_in[7];
  const float* al2  = (const float*)d_in[8];
  const float* ar2  = (const float*)d_in[9];
  const float* b2   = (const float*)d_in[10];
  const float* ln1w = (const float*)d_in[11];
  const float* ln1b = (const float*)d_in[12];
  const float* ln2w = (const float*)d_in[13];
  const float* ln2b = (const float*)d_in[14];
  const float* tc1w = (const float*)d_in[15];
  const float* tc1b = (const float*)d_in[16];
  const float* ln3w = (const float*)d_in[17];
  const float* ln3b = (const float*)d_in[18];
  const float* tc2w = (const float*)d_in[19];
  const float* tc2b = (const float*)d_in[20];
  const float* fcw  = (const float*)d_in[21];
  const float* fcb  = (const float*)d_in[22];
  int E = in_sizes[1];

  unsigned short* U = (unsigned short*)d_ws;
  unsigned short* feat = U + 0;            // 16,777,216 shorts
  unsigned short* x1   = U + 16777216;     // 8,388,608
  unsigned short* x2   = U + 25165824;     // 16,777,216
  unsigned short* xt1  = U + 0;            // reuse feat after GAT2
  unsigned short* xt2  = U + 12582912;     // overlaps dead x1 tail
  unsigned short* wf1  = U + 41943040;     // 10368
  unsigned short* wf2  = wf1 + 10368;      // 10368
  unsigned short* wc1  = wf2 + 10368;      // 20480
  unsigned short* wc2  = wc1 + 20480;      // 4096
  float* F = (float*)(wc2 + 4096);
  float* el1 = F;                    // 131072
  float* er1 = el1 + 131072;         // 131072
  float* el2 = er1 + 131072;         // 262144
  float* er2 = el2 + 262144;         // 262144
  float2* pg1 = (float2*)(er2 + 262144);   // 64*2048
  float2* pg2 = pg1 + 131072;              // 128*2048
  float2* pr3 = pg2 + 262144;              // 196608
  float* mu1  = (float*)(pr3 + 196608);    // 64
  float* inv1 = mu1 + 64;
  float* mu2  = inv1 + 64;                 // 128
  float* inv2 = mu2 + 128;
  float* mu3  = inv2 + 128;                // 96
  float* inv3 = mu3 + 96;
  int* counts = (int*)(inv3 + 96);
  int* cursor = counts + 2048;
  int* rs     = cursor + 2048;       // 2049
  int* csrsrc = rs + 2049;           // E

  int eb = (E+255)/256;

  k_prep<<<6,256,0,stream>>>(W1,al1,ar1, W2,al2,ar2, tc1w, tc2w, wf1, wf2, wc1, wc2, counts);
  k_count<<<eb,256,0,stream>>>(dst, E, counts);
  k_scan<<<1,256,0,stream>>>(counts, rs, cursor);
  k_fill<<<eb,256,0,stream>>>(dst, src, E, cursor, csrsrc);

  // GAT layer 1
  k_featm<4,2,false,false><<<1024,256,0,stream>>>(x, wf1, nullptr,nullptr,nullptr,nullptr, feat, el1, er1);
  k_gat_agg<4><<<2048,256,0,stream>>>(feat, el1, er1, rs, csrsrc, b1, (unsigned int*)x1, pg1);
  k_lnfin<<<64,256,0,stream>>>(pg1, mu1, inv1, 0, 2);

  // GAT layer 2 (LN1 fused)
  k_featm<8,3,true,true><<<2048,256,0,stream>>>(x1, wf2, mu1, inv1, ln1w, ln1b, feat, el2, er2);
  k_gat_agg<8><<<2048,256,0,stream>>>(feat, el2, er2, rs, csrsrc, b2, (unsigned int*)x2, pg2);
  k_lnfin<<<128,256,0,stream>>>(pg2, mu2, inv2, 0, 3);

  // tc1 (5-tap, 16->12), LN2 fused, emits LN3 partials
  k_convT<16,12,5,true><<<1536,256,0,stream>>>(x2, mu2, inv2, ln2w, ln2b, wc1, tc1b, xt1, pr3);
  k_lnfin<<<96,256,0,stream>>>(pr3, mu3, inv3, 1, 0);

  // tc2 (1x1), LN3 fused
  k_convT<12,12,1,false><<<1536,256,0,stream>>>(xt1, mu3, inv3, ln3w, ln3b, wc2, tc2b, xt2, nullptr);

  // final fc
  k_fc<<<256,256,0,stream>>>(xt2, fcw, fcb, (float*)d_out);
}